// Round 15
// baseline (280.709 us; speedup 1.0000x reference)
//
#include <hip/hip_runtime.h>
#include <stdint.h>

#define BB 128
#define TT 3000
#define CC 64
#define LL 128
// S = 2L+1 = 257 ; states 0..255 on 2 waves x 64 lanes x 2 states; 256 via tail
#define NEGf (-1e30f)
#define LOG2E 1.4426950408889634f
#define LN2f 0.6931471805599453f
#define F 12                  // frames per ring chunk; 3000 = 250 * 12
#define NCH 250
#define NPH (NCH + 1)         // wave1 lags 1 chunk
#define NULLM (-30000)        // null exponent (log2 scale), far below any live m
#define LSE_BLOCKS 512

typedef float f32x2 __attribute__((ext_vector_type(2)));
typedef float f32x4 __attribute__((ext_vector_type(4)));

__device__ __forceinline__ float fexp2(float x){ return __builtin_amdgcn_exp2f(x); }
__device__ __forceinline__ float flog2(float x){ return __builtin_amdgcn_logf(x); }
__device__ __forceinline__ int dpp_shr1_i(int x, int old){
    return __builtin_amdgcn_update_dpp(old, x, 0x138, 0xF, 0xF, false);
}
__device__ __forceinline__ float dpp_shr1_f(float x, float old){
    int r = __builtin_amdgcn_update_dpp(__float_as_int(old), __float_as_int(x),
                                        0x138, 0xF, 0xF, false);
    return __int_as_float(r);
}
#define DPPMAXT(x,c) fmaxf((x),__int_as_float(__builtin_amdgcn_update_dpp(0,__float_as_int(x),(c),0xF,0xF,true)))
#define DPPADDT(x,c) ((x)+__int_as_float(__builtin_amdgcn_update_dpp(0,__float_as_int(x),(c),0xF,0xF,true)))
#define RED64(OP,x) { x=OP(x,0x111); x=OP(x,0x112); x=OP(x,0x114); x=OP(x,0x118); x=OP(x,0x142); x=OP(x,0x143); }

// Fused kernel, 512 threads/block.
// Scan blocks: waves 0,1 = consumers. Lane l of wave W owns states 128W+2l
// (even, a0) and 128W+2l+1 (odd, a1), each as (m:int, r:f32 in [0.25,1)) with
// value 2^m * r. lse steps are EXACT linear arithmetic: max_i32 + v_ldexp_f32
// + add + bit-frexp — zero transcendentals on the serial chain. Wave1 lags one
// chunk; boundary (state 127) passes as (m,r) pairs via mod-3 LDS ring.
// Waves 2-7 = producers (T14 split: load chunk c+2, store chunk c+1), staging
// em as (m_e, r_e) pairs. State 256 via the verified R13/R14 tail pass.
__global__ __launch_bounds__(512) void fused_kernel(const float* __restrict__ in,
                                                    const int* __restrict__ tgt,
                                                    float* __restrict__ lse,
                                                    float* __restrict__ ll2){
    __shared__ __align__(16) float emR[3][F][258]; // frame: 128 (m,r) target pairs + blank pair at [256]
    __shared__ __align__(16) float bndR[3][F][2];  // state-127 (m,r) per step
    __shared__ __align__(16) float nullBnd[24];    // null pairs for wave0's uniform reads
    __shared__ float laL[3008];                    // la255(t) log2 (wave1 lane63)
    __shared__ float lbL[3008];                    // lemB(t) log2 (producers)
    if (blockIdx.x < BB) {
        const int b = blockIdx.x;
        const int wave = threadIdx.x >> 6;
        const int lane = threadIdx.x & 63;
        const float* fb = in + (size_t)b * TT * CC;
        const uint32_t em_base  = (uint32_t)(uintptr_t)&emR[0][0][0];
        const uint32_t bnd_base = (uint32_t)(uintptr_t)&bndR[0][0][0];

        if (wave < 2) {
            const int W = wave;
            __builtin_amdgcn_s_setprio(1);
            if (W == 0) {
                if (lane < 12) { nullBnd[2*lane] = __int_as_float(NULLM); nullBnd[2*lane+1] = 0.5f; }
                if (lane == 0) { bndR[0][0][0] = __int_as_float(NULLM); bndR[0][0][1] = 0.5f; }
                if (lane < 8) { laL[3000+lane] = NEGf; lbL[3000+lane] = 0.f; }
            }
            int a0m = NULLM, a1m = NULLM; float a0r = 0.5f, a1r = 0.5f;
            if (W == 0 && lane == 0) { a0m = 1; a0r = 0.5f; }   // alpha = 1 pre-state
            const uint32_t em1_ad = em_base + (uint32_t)((64*W + lane) * 8);
            const uint32_t emB_ad = em_base + 1024u;            // pair index 128
            const uint32_t nb_ad  = (uint32_t)(uintptr_t)&nullBnd[0];
            __syncthreads();
            for (int ph = 0; ph < NPH; ++ph) {
                const int x = ph - W;
                if (x >= 0 && x < NCH) {
                    const uint32_t buf = (uint32_t)(x % 3);
                    const uint32_t ra = em1_ad + buf*12384u;
                    const uint32_t rb = emB_ad + buf*12384u;
                    const uint32_t rq = W ? (bnd_base + buf*96u) : nb_ad;
                    f32x4 B4[6]; f32x2 E1[F], EB[F];
                    asm volatile("ds_read_b128 %0, %1 offset:0"  : "=v"(B4[0]) : "v"(rq));
                    asm volatile("ds_read_b128 %0, %1 offset:16" : "=v"(B4[1]) : "v"(rq));
                    asm volatile("ds_read_b128 %0, %1 offset:32" : "=v"(B4[2]) : "v"(rq));
                    asm volatile("ds_read_b128 %0, %1 offset:48" : "=v"(B4[3]) : "v"(rq));
                    asm volatile("ds_read_b128 %0, %1 offset:64" : "=v"(B4[4]) : "v"(rq));
                    asm volatile("ds_read_b128 %0, %1 offset:80" : "=v"(B4[5]) : "v"(rq));
                    asm volatile("ds_read_b64 %0, %1 offset:0"    : "=v"(E1[0]) : "v"(ra));
                    asm volatile("ds_read_b64 %0, %1 offset:0"    : "=v"(EB[0]) : "v"(rb));
                    asm volatile("ds_read_b64 %0, %1 offset:1032" : "=v"(E1[1]) : "v"(ra));
                    asm volatile("ds_read_b64 %0, %1 offset:1032" : "=v"(EB[1]) : "v"(rb));
                    asm volatile("ds_read_b64 %0, %1 offset:2064" : "=v"(E1[2]) : "v"(ra));
                    asm volatile("ds_read_b64 %0, %1 offset:2064" : "=v"(EB[2]) : "v"(rb));
                    int hm[F]; float hr[F];
                    #pragma unroll
                    for (int j = 0; j < F; ++j) {
                        if (j + 3 < F) {
                            asm volatile("ds_read_b64 %0, %1 offset:%2"
                                         : "=v"(E1[j+3]) : "v"(ra), "n"((j+3)*1032));
                            asm volatile("ds_read_b64 %0, %1 offset:%2"
                                         : "=v"(EB[j+3]) : "v"(rb), "n"((j+3)*1032));
                            asm volatile("s_waitcnt lgkmcnt(6)" ::: "memory");
                        } else if (j + 3 == F) {
                            asm volatile("s_waitcnt lgkmcnt(4)" ::: "memory");
                        } else if (j + 2 == F) {
                            asm volatile("s_waitcnt lgkmcnt(2)" ::: "memory");
                        } else {
                            asm volatile("s_waitcnt lgkmcnt(0)" ::: "memory");
                        }
                        __builtin_amdgcn_sched_barrier(0);   // rule #18
                        const int   bjm = __float_as_int((j&1) ? B4[j>>1].z : B4[j>>1].x);
                        const float bjr = (j&1) ? B4[j>>1].w : B4[j>>1].y;
                        const int   e1m = __float_as_int(E1[j].x); const float e1r = E1[j].y;
                        const int   ebm = __float_as_int(EB[j].x); const float ebr = EB[j].y;
                        int p1m = dpp_shr1_i(a1m, NULLM);          // state 2l-1 (t-1)
                        float p1r = dpp_shr1_f(a1r, 0.5f);
                        p1m = (lane == 0) ? bjm : p1m;             // boundary / null inject
                        p1r = (lane == 0) ? bjr : p1r;
                        // even: a0' = emB (x) (a0 (+) p1)   [exact extended-range f32]
                        int Mt = (a0m > p1m) ? a0m : p1m;
                        float rs = ldexpf(a0r, a0m - Mt) + ldexpf(p1r, p1m - Mt);
                        int ui = __float_as_int(rs);
                        int n0m = Mt + ((ui >> 23) - 126) + ebm;
                        float n0r = __int_as_float((ui & 0x7FFFFF) | 0x3F000000) * ebr;
                        // odd: a1' = em1 (x) (a1 (+) a0 (+) p1)
                        int Mu = (a1m > a0m) ? a1m : a0m; Mu = (Mu > p1m) ? Mu : p1m;
                        float ru = ldexpf(a1r, a1m - Mu) + ldexpf(a0r, a0m - Mu)
                                 + ldexpf(p1r, p1m - Mu);
                        int uj = __float_as_int(ru);
                        int n1m = Mu + ((uj >> 23) - 126) + e1m;
                        float n1r = __int_as_float((uj & 0x7FFFFF) | 0x3F000000) * e1r;
                        a0m = n0m; a0r = n0r; a1m = n1m; a1r = n1r;
                        hm[j] = a1m; hr[j] = a1r;
                    }
                    // batched hand-off, lane63 only, off-chain
                    if (W == 0 && lane == 63) {
                        float* s0 = &bndR[x % 3][0][0];
                        #pragma unroll
                        for (int j = 0; j < F-1; ++j) {
                            s0[(j+1)*2] = __int_as_float(hm[j]); s0[(j+1)*2+1] = hr[j];
                        }
                        float* s1 = &bndR[(x+1) % 3][0][0];
                        s1[0] = __int_as_float(hm[F-1]); s1[1] = hr[F-1];
                    }
                    if (W == 1 && lane == 63) {
                        #pragma unroll
                        for (int j = 0; j < F; ++j)
                            laL[x*F + j] = (float)hm[j] + flog2(hr[j]);
                    }
                    asm volatile("s_waitcnt lgkmcnt(0)" ::: "memory");
                }
                __syncthreads();
            }
            __syncthreads();   // tail barrier (all waves)
            if (W == 0) {
                // la256(T-1) = lse_{tau<=T-2}( la255(tau) + CBtot - CB(tau) )  [R13-verified]
                const int base = lane*47;               // 3008 = 64*47
                float seg = 0.f;
                for (int k = 0; k < 47; ++k) seg += lbL[base+k];
                float inc = seg;
                #pragma unroll
                for (int d = 1; d < 64; d <<= 1) {
                    float t = __shfl_up(inc, d, 64);
                    if (lane >= d) inc += t;
                }
                float CBtot = __int_as_float(__builtin_amdgcn_readlane(__float_as_int(inc), 63));
                float ex = inc - seg;
                float cb = ex, gm = NEGf;
                for (int k = 0; k < 47; ++k) {
                    int idx = base+k;
                    cb += lbL[idx];
                    float g = laL[idx] + (CBtot - cb);
                    g = (idx == 2999) ? NEGf : g;
                    gm = fmaxf(gm, g);
                }
                RED64(DPPMAXT, gm);
                float gmax = __int_as_float(__builtin_amdgcn_readlane(__float_as_int(gm), 63));
                cb = ex; float se = 0.f;
                for (int k = 0; k < 47; ++k) {
                    int idx = base+k;
                    cb += lbL[idx];
                    float g = laL[idx] + (CBtot - cb);
                    g = (idx == 2999) ? NEGf : g;
                    se += fexp2(g - gmax);
                }
                RED64(DPPADDT, se);
                float S = __int_as_float(__builtin_amdgcn_readlane(__float_as_int(se), 63));
                float la256 = gmax + flog2(S);
                float la255f = laL[2999];
                float m = fmaxf(la255f, la256);
                float r = m + flog2(1.0f + fexp2(-fabsf(la255f - la256)));
                if (lane == 0) ll2[b] = r;
            }
        } else {
            // producers: wave p handles frames p, p+6; T14 load/store split
            const int p = wave - 2;                  // 0..5
            const int t0 = tgt[b*LL + lane];         // target for em slot lane
            const int t1 = tgt[b*LL + 64 + lane];    // target for em slot 64+lane
            float v0[2], v1[2], vb[2];
            auto loadc = [&](int cc){
                const float* cbase = fb + (size_t)cc * F * CC;
                #pragma unroll
                for (int k = 0; k < 2; ++k) {
                    const float* fr = cbase + (p + 6*k) * CC;
                    v0[k] = fr[t0]; v1[k] = fr[t1]; vb[k] = fr[63];
                }
            };
            auto storec = [&](int cc){
                const int buf = cc % 3;
                #pragma unroll
                for (int k = 0; k < 2; ++k) {
                    const int f = p + 6*k;
                    float x0 = v0[k] * LOG2E; float f0 = floorf(x0);
                    *(f32x2*)&emR[buf][f][2*lane] =
                        (f32x2){__int_as_float((int)f0 + 1), fexp2(x0 - f0 - 1.0f)};
                    float x1 = v1[k] * LOG2E; float f1 = floorf(x1);
                    *(f32x2*)&emR[buf][f][2*(64+lane)] =
                        (f32x2){__int_as_float((int)f1 + 1), fexp2(x1 - f1 - 1.0f)};
                    if (lane == 0) {
                        float xb = vb[k] * LOG2E; float fbl = floorf(xb);
                        *(f32x2*)&emR[buf][f][256] =
                            (f32x2){__int_as_float((int)fbl + 1), fexp2(xb - fbl - 1.0f)};
                        lbL[cc*F + f] = xb;
                    }
                }
            };
            loadc(0); storec(0); loadc(1);
            __syncthreads();
            for (int ph = 0; ph < NPH; ++ph) {
                if (ph + 1 < NCH) storec(ph + 1);
                if (ph + 2 < NCH) loadc(ph + 2);
                __syncthreads();
            }
            __syncthreads();   // tail barrier
        }
        return;
    }
    // ---- softmax normalizer: one wave per (b,t) row, grid-strided ----
    int wv = (blockIdx.x - BB) * 8 + (threadIdx.x >> 6);
    int lane = threadIdx.x & 63;
    const int stride = LSE_BLOCKS * 8;
    for (int row = wv; row < BB * TT; row += stride) {
        float x = in[(size_t)row * CC + lane];
        float m = x;
        #pragma unroll
        for (int d = 32; d >= 1; d >>= 1) m = fmaxf(m, __shfl_xor(m, d, 64));
        float s = fexp2((x - m) * LOG2E);
        #pragma unroll
        for (int d = 32; d >= 1; d >>= 1) s += __shfl_xor(s, d, 64);
        if (lane == 0) lse[row] = m + flog2(s) * LN2f;
    }
}

// per-batch loss_b = sum_t lse_nat[b,t] - ll2[b]*ln2
__global__ __launch_bounds__(256) void bsum_kernel(const float* __restrict__ lse,
                                                   const float* __restrict__ ll2,
                                                   float* __restrict__ lossb) {
    __shared__ float red[256];
    int b = blockIdx.x;
    float s = 0.f;
    for (int i = threadIdx.x; i < TT; i += 256) s += lse[(size_t)b * TT + i];
    red[threadIdx.x] = s;
    __syncthreads();
    #pragma unroll
    for (int w = 128; w >= 1; w >>= 1) {
        if (threadIdx.x < w) red[threadIdx.x] += red[threadIdx.x + w];
        __syncthreads();
    }
    if (threadIdx.x == 0) lossb[b] = red[0] - ll2[b] * LN2f;
}

// mean over batch
__global__ __launch_bounds__(64) void final_kernel(const float* __restrict__ lossb,
                                                   float* __restrict__ out) {
    int lane = threadIdx.x;
    float v = lossb[lane] + lossb[lane + 64];
    #pragma unroll
    for (int d = 32; d >= 1; d >>= 1) v += __shfl_xor(v, d, 64);
    if (lane == 0) out[0] = v / (float)BB;
}

extern "C" void kernel_launch(void* const* d_in, const int* in_sizes, int n_in,
                              void* d_out, int out_size, void* d_ws, size_t ws_size,
                              hipStream_t stream) {
    const float* in = (const float*)d_in[0];
    const int* tg = (const int*)d_in[1];
    float* out = (float*)d_out;
    float* lse = (float*)d_ws;                 // B*T floats
    float* ll2 = lse + (size_t)BB * TT;        // B floats
    float* lossb = ll2 + BB;                   // B floats

    hipLaunchKernelGGL(fused_kernel, dim3(BB + LSE_BLOCKS), dim3(512), 0, stream,
                       in, tg, lse, ll2);
    hipLaunchKernelGGL(bsum_kernel, dim3(BB), dim3(256), 0, stream, lse, ll2, lossb);
    hipLaunchKernelGGL(final_kernel, dim3(1), dim3(64), 0, stream, lossb, out);
}